// Round 1
// baseline (52437.122 us; speedup 1.0000x reference)
//
#include <hip/hip_runtime.h>

namespace {
constexpr int BB   = 32;    // batch
constexpr int TT   = 2048;  // time
constexpr int HH   = 512;   // hidden (== D)
constexpr int NBLK = 128;   // blocks per layer
constexpr int RING = 4;     // h ring slots (must be >= 3)
constexpr int KC   = 128;   // k-chunk staged in LDS
constexpr int NCH  = 8;     // 1024 / KC
constexpr int YSZ  = BB * TT * HH;       // y elements
constexpr int HFO  = YSZ;                // h_final offset
constexpr int CFO  = YSZ + 2 * BB * HH;  // c_final offset
}

__device__ __forceinline__ float sigf(float v)  { return 1.0f / (1.0f + __expf(-v)); }
__device__ __forceinline__ float tanh_(float v) { return 1.0f - 2.0f / (__expf(2.0f * v) + 1.0f); }

// LDS swizzles: spread bank usage; xor only touches bits 2..4 -> float4-aligned, bijective.
__device__ __forceinline__ int uswz(int b, int kc) {
  return (b << 7) + (kc ^ ((b & 7) << 2) ^ (((kc >> 5) & 3) << 2));
}
__device__ __forceinline__ int wswz(int row, int k) {
  return (row << 10) + (k ^ ((row >> 2) << 3) ^ (((k >> 5) & 3) << 2));
}

__global__ __launch_bounds__(256, 1) void lstm_persist(
    const float* __restrict__ x,
    const float* __restrict__ Wih0, const float* __restrict__ Whh0,
    const float* __restrict__ bih0, const float* __restrict__ bhh0,
    const float* __restrict__ Wih1, const float* __restrict__ Whh1,
    const float* __restrict__ bih1, const float* __restrict__ bhh1,
    const float* __restrict__ h0c, const float* __restrict__ c0c,
    float* __restrict__ out, float* __restrict__ ring, int* __restrict__ cnt)
{
  // 64 KB weights + 16 KB staging = 80 KB -> 2 blocks/CU capacity, 256 blocks always resident.
  __shared__ __align__(16) float Wsh[16 * 1024];
  __shared__ __align__(16) float ubuf[BB * KC];
  float* gbuf = ubuf;  // aliased: gate buffer (512 floats) used only between barriers after last chunk

  const int tid   = (int)threadIdx.x;
  const int layer = (int)(blockIdx.x >> 7);        // 0..1
  const int lb    = (int)(blockIdx.x & (NBLK - 1));
  const int j0    = lb << 2;                        // 4 hidden columns per block

  const float* Wih = layer ? Wih1 : Wih0;
  const float* Whh = layer ? Whh1 : Whh0;
  const float* bih = layer ? bih1 : bih0;
  const float* bhh = layer ? bhh1 : bhh0;

  // Load W' = [Wih | Whh] rows {g*512 + j0 + jj} into LDS (swizzled). Coalesced in k.
  for (int idx = tid; idx < 16 * 1024; idx += 256) {
    const int row = idx >> 10;          // 0..15 = gate*4 + jj
    const int k   = idx & 1023;
    const int rg  = ((row >> 2) << 9) + j0 + (row & 3);
    const float v = (k < 512) ? Wih[(rg << 9) + k] : Whh[(rg << 9) + (k - 512)];
    Wsh[wswz(row, k)] = v;
  }

  // Elementwise-thread state: c in registers, bias in registers.
  float creg = 0.0f;
  float bias_[4] = {0.f, 0.f, 0.f, 0.f};
  if (tid < 128) {
    const int jj = tid & 3;
    creg = c0c[layer * HH + j0 + jj];
#pragma unroll
    for (int g = 0; g < 4; ++g) {
      const int rg = (g << 9) + j0 + jj;
      bias_[g] = bih[rg] + bhh[rg];
    }
  }

  const int kt = tid & 7;          // k-split id (8)
  const int rt = (tid >> 3) & 3;   // gate tile (4)
  const int bt = tid >> 5;         // batch tile (8)

#pragma unroll 1
  for (int s = 0; s < TT; ++s) {
    // ---------------- wait ----------------
    if (tid == 0) {
      if (layer == 0) {
        if (s > 0) {
          const int need = s * NBLK;  // all L0 blocks finished step s-1 (h[s-1] ready)
          while (__hip_atomic_load(&cnt[0], __ATOMIC_RELAXED, __HIP_MEMORY_SCOPE_AGENT) < need)
            __builtin_amdgcn_s_sleep(1);
        }
        if (s >= RING) {
          const int need = (s - RING + 1) * NBLK;  // L1 consumed slot we're about to overwrite
          while (__hip_atomic_load(&cnt[1], __ATOMIC_RELAXED, __HIP_MEMORY_SCOPE_AGENT) < need)
            __builtin_amdgcn_s_sleep(1);
        }
      } else {
        const int need = (s + 1) * NBLK;  // y0[s] available
        while (__hip_atomic_load(&cnt[0], __ATOMIC_RELAXED, __HIP_MEMORY_SCOPE_AGENT) < need)
          __builtin_amdgcn_s_sleep(1);
        if (s > 0) {
          const int need1 = s * NBLK;  // our own h1[s-1] (in d_out) fully written
          while (__hip_atomic_load(&cnt[1], __ATOMIC_RELAXED, __HIP_MEMORY_SCOPE_AGENT) < need1)
            __builtin_amdgcn_s_sleep(1);
        }
      }
      __threadfence();  // acquire: invalidate caches so fresh ring/out data is visible CU-wide
    }
    __syncthreads();

    // ---------------- gates = [x_t | h_prev] @ W'^T ----------------
    float4 acc[4][4];
#pragma unroll
    for (int ri = 0; ri < 4; ++ri)
#pragma unroll
      for (int bi = 0; bi < 4; ++bi)
        acc[ri][bi] = make_float4(0.f, 0.f, 0.f, 0.f);

#pragma unroll 1
    for (int ch = 0; ch < NCH; ++ch) {
      // stage 32x128 chunk of the concatenated input into LDS (coalesced float4)
#pragma unroll
      for (int i = 0; i < 4; ++i) {
        const int f   = tid + (i << 8);   // 0..1023 float4 id
        const int b   = f >> 5;
        const int kc4 = (f & 31) << 2;
        float4 v;
        if (layer == 0) {
          if (ch < 4) {
            const int kg = (ch << 7) + kc4;
            v = *(const float4*)(x + ((size_t)((b << 11) + s) << 9) + kg);
          } else {
            const int kh = ((ch - 4) << 7) + kc4;
            if (s == 0) v = *(const float4*)(h0c + kh);
            else        v = *(const float4*)(ring + ((((s - 1) & (RING - 1)) * BB + b) << 9) + kh);
          }
        } else {
          if (ch < 4) {
            const int kg = (ch << 7) + kc4;
            v = *(const float4*)(ring + (((s & (RING - 1)) * BB + b) << 9) + kg);
          } else {
            const int kh = ((ch - 4) << 7) + kc4;
            if (s == 0) v = *(const float4*)(h0c + HH + kh);
            else        v = *(const float4*)(out + ((size_t)((b << 11) + (s - 1)) << 9) + kh);
          }
        }
        *(float4*)(ubuf + uswz(b, kc4)) = v;
      }
      __syncthreads();
      // accumulate: 4 gates x 4 batches per thread over this thread's k-slice
#pragma unroll
      for (int kk = 0; kk < 16; kk += 4) {
        const int kc4 = (kt << 4) + kk;
        float4 u[4], w[4];
#pragma unroll
        for (int bi = 0; bi < 4; ++bi) {
          const int b = (bt << 2) + bi;
          u[bi] = *(const float4*)(ubuf + uswz(b, kc4));
        }
        const int kx = (ch << 7) + kc4;
#pragma unroll
        for (int ri = 0; ri < 4; ++ri) {
          const int row = (rt << 2) + ri;
          w[ri] = *(const float4*)(Wsh + wswz(row, kx));
        }
#pragma unroll
        for (int ri = 0; ri < 4; ++ri)
#pragma unroll
          for (int bi = 0; bi < 4; ++bi) {
            acc[ri][bi].x = fmaf(u[bi].x, w[ri].x, acc[ri][bi].x);
            acc[ri][bi].y = fmaf(u[bi].y, w[ri].y, acc[ri][bi].y);
            acc[ri][bi].z = fmaf(u[bi].z, w[ri].z, acc[ri][bi].z);
            acc[ri][bi].w = fmaf(u[bi].w, w[ri].w, acc[ri][bi].w);
          }
      }
      __syncthreads();
    }

    // ---------------- reduce k-split, gather gates ----------------
#pragma unroll
    for (int ri = 0; ri < 4; ++ri) {
#pragma unroll
      for (int bi = 0; bi < 4; ++bi) {
        float v = (acc[ri][bi].x + acc[ri][bi].y) + (acc[ri][bi].z + acc[ri][bi].w);
        v += __shfl_xor(v, 1, 64);
        v += __shfl_xor(v, 2, 64);
        v += __shfl_xor(v, 4, 64);
        if (kt == 0) gbuf[(((rt << 2) + ri) << 5) + (bt << 2) + bi] = v;
      }
    }
    __syncthreads();

    // ---------------- elementwise LSTM cell + stores ----------------
    if (tid < 128) {
      const int jj = tid & 3;
      const int b  = tid >> 2;
      const float gi = gbuf[((0 + jj) << 5) + b] + bias_[0];
      const float gf = gbuf[((4 + jj) << 5) + b] + bias_[1];
      const float gg = gbuf[((8 + jj) << 5) + b] + bias_[2];
      const float go = gbuf[((12 + jj) << 5) + b] + bias_[3];
      const float cn = sigf(gf) * creg + sigf(gi) * tanh_(gg);
      const float hn = sigf(go) * tanh_(cn);
      creg = cn;
      const int j = j0 + jj;
      if (layer == 0) {
        ring[(((s & (RING - 1)) * BB + b) << 9) + j] = hn;
        if (s == TT - 1) out[(size_t)HFO + (b << 9) + j] = hn;       // h_final[0]
      } else {
        out[((size_t)((b << 11) + s) << 9) + j] = hn;                 // y
        if (s == TT - 1) out[(size_t)HFO + ((BB + b) << 9) + j] = hn; // h_final[1]
      }
    }
    __syncthreads();  // drains all stores (vmcnt(0) before s_barrier)
    if (tid == 0) {
      // release: L2 writeback happens as part of agent-scope release RMW
      __hip_atomic_fetch_add(&cnt[layer], 1, __ATOMIC_RELEASE, __HIP_MEMORY_SCOPE_AGENT);
    }
  }

  // ---------------- c_final ----------------
  if (tid < 128) {
    const int jj = tid & 3;
    const int b  = tid >> 2;
    out[(size_t)CFO + ((layer * BB + b) << 9) + (j0 + jj)] = creg;
  }
}

extern "C" void kernel_launch(void* const* d_in, const int* in_sizes, int n_in,
                              void* d_out, int out_size, void* d_ws, size_t ws_size,
                              hipStream_t stream) {
  (void)in_sizes; (void)n_in; (void)out_size; (void)ws_size;
  const float* x    = (const float*)d_in[0];
  const float* Wih0 = (const float*)d_in[1];
  const float* Whh0 = (const float*)d_in[2];
  const float* bih0 = (const float*)d_in[3];
  const float* bhh0 = (const float*)d_in[4];
  const float* Wih1 = (const float*)d_in[5];
  const float* Whh1 = (const float*)d_in[6];
  const float* bih1 = (const float*)d_in[7];
  const float* bhh1 = (const float*)d_in[8];
  const float* h0   = (const float*)d_in[9];
  const float* c0   = (const float*)d_in[10];

  float* out  = (float*)d_out;
  float* ring = (float*)d_ws;                                  // RING*B*H floats = 256 KB
  int*   cnt  = (int*)((char*)d_ws + (size_t)RING * BB * HH * sizeof(float));

  // progress counters must be zero every call (graph replays don't re-poison)
  hipMemsetAsync(cnt, 0, 64, stream);

  hipLaunchKernelGGL(lstm_persist, dim3(2 * NBLK), dim3(256), 0, stream,
                     x, Wih0, Whh0, bih0, bhh0, Wih1, Whh1, bih1, bhh1,
                     h0, c0, out, ring, cnt);
}

// Round 2
// 29640.485 us; speedup vs baseline: 1.7691x; 1.7691x over previous
//
#include <hip/hip_runtime.h>

namespace {
constexpr int BB   = 32;    // batch
constexpr int TT   = 2048;  // time
constexpr int HH   = 512;   // hidden (== D)
constexpr int NBLK = 128;   // blocks per layer
constexpr int RING = 4;     // ring slots
constexpr int YSZ  = BB * TT * HH;
constexpr int HFO  = YSZ;
constexpr int CFO  = YSZ + 2 * BB * HH;
}

typedef float f32x4 __attribute__((ext_vector_type(4)));

__device__ __forceinline__ float sigf(float v)  { return 1.0f / (1.0f + __expf(-v)); }
__device__ __forceinline__ float tanh_(float v) { return 1.0f - 2.0f / (__expf(2.0f * v) + 1.0f); }

__device__ __forceinline__ int uswz(int b, int kc) {
  return (b << 7) + (kc ^ ((b & 7) << 2) ^ (((kc >> 5) & 3) << 2));
}
__device__ __forceinline__ int wswz(int row, int k) {
  return (row << 10) + (k ^ ((row >> 2) << 3) ^ (((k >> 5) & 3) << 2));
}

// Coherent (agent-scope) 16B load: sc1 bypasses per-CU L1 and per-XCD L2, hits
// the shared coherence point. Single coalesced instruction -> no traffic blowup.
__device__ __forceinline__ f32x4 ld_x4_coh(const float* p) {
  f32x4 r;
  asm volatile("global_load_dwordx4 %0, %1, off sc1" : "=v"(r) : "v"(p) : "memory");
  return r;
}
__device__ __forceinline__ void st_coh(float* p, float v) {
  __hip_atomic_store(p, v, __ATOMIC_RELAXED, __HIP_MEMORY_SCOPE_AGENT);
}
__device__ __forceinline__ void poll_ge(int* p, int need) {
  while (__hip_atomic_load(p, __ATOMIC_RELAXED, __HIP_MEMORY_SCOPE_AGENT) < need)
    __builtin_amdgcn_s_sleep(2);
}

__global__ __launch_bounds__(256, 1) void lstm_persist(
    const float* __restrict__ x,
    const float* __restrict__ Wih0, const float* __restrict__ Whh0,
    const float* __restrict__ bih0, const float* __restrict__ bhh0,
    const float* __restrict__ Wih1, const float* __restrict__ Whh1,
    const float* __restrict__ bih1, const float* __restrict__ bhh1,
    const float* __restrict__ h0c, const float* __restrict__ c0c,
    float* __restrict__ out, float* __restrict__ ring, float* __restrict__ ring1,
    int* __restrict__ cnt)
{
  __shared__ __align__(16) float Wsh[16 * 1024];
  __shared__ __align__(16) float ubuf[BB * 128];
  float* gbuf = ubuf;  // alias: 512-float gate buffer between (C)/(E) barriers

  const int tid   = (int)threadIdx.x;
  const int layer = (int)(blockIdx.x >> 7);
  const int lb    = (int)(blockIdx.x & (NBLK - 1));
  const int j0    = lb << 2;

  const float* Wih = layer ? Wih1 : Wih0;
  const float* Whh = layer ? Whh1 : Whh0;
  const float* bih = layer ? bih1 : bih0;
  const float* bhh = layer ? bhh1 : bhh0;

  for (int idx = tid; idx < 16 * 1024; idx += 256) {
    const int row = idx >> 10;
    const int k   = idx & 1023;
    const int rg  = ((row >> 2) << 9) + j0 + (row & 3);
    const float v = (k < 512) ? Wih[(rg << 9) + k] : Whh[(rg << 9) + (k - 512)];
    Wsh[wswz(row, k)] = v;
  }

  float creg = 0.0f;
  float bias_[4] = {0.f, 0.f, 0.f, 0.f};
  if (tid < 128) {
    const int jj = tid & 3;
    creg = c0c[layer * HH + j0 + jj];
#pragma unroll
    for (int g = 0; g < 4; ++g) {
      const int rg = (g << 9) + j0 + jj;
      bias_[g] = bih[rg] + bhh[rg];
    }
  }

  const int kt = tid & 7;
  const int rt = (tid >> 3) & 3;
  const int bt = tid >> 5;

  f32x4 r4[4];  // staging prefetch registers (loop-carried across chunks)

#pragma unroll 1
  for (int s = 0; s < TT; ++s) {
    f32x4 acc[4][4];
#pragma unroll
    for (int ri = 0; ri < 4; ++ri)
#pragma unroll
      for (int bi = 0; bi < 4; ++bi)
        acc[ri][bi] = (f32x4){0.f, 0.f, 0.f, 0.f};

    // Logical chunk order: L0 = [x0..x3, h0..h3]; L1 = [h1_0..h1_3, ring0..ring3].
    auto load_chunk = [&](int i) {
#pragma unroll
      for (int j = 0; j < 4; ++j) {
        const int f   = tid + (j << 8);
        const int b   = f >> 5;
        const int kc4 = (f & 31) << 2;
        if (layer == 0) {
          if (i < 4) {
            r4[j] = *(const f32x4*)(x + ((size_t)((b << 11) + s) << 9) + (i << 7) + kc4);
          } else if (s == 0) {
            r4[j] = *(const f32x4*)(h0c + ((i - 4) << 7) + kc4);
          } else {
            r4[j] = ld_x4_coh(ring + ((((s - 1) & (RING - 1)) * BB + b) << 9) + ((i - 4) << 7) + kc4);
          }
        } else {
          if (i < 4) {
            if (s == 0) r4[j] = *(const f32x4*)(h0c + HH + (i << 7) + kc4);
            else        r4[j] = ld_x4_coh(ring1 + ((((s - 1) & (RING - 1)) * BB + b) << 9) + (i << 7) + kc4);
          } else {
            r4[j] = ld_x4_coh(ring + (((s & (RING - 1)) * BB + b) << 9) + ((i - 4) << 7) + kc4);
          }
        }
      }
    };
    auto compute = [&](int i) {
      const int kc = (layer == 0) ? i : ((i < 4) ? 4 + i : i - 4);
#pragma unroll
      for (int kk = 0; kk < 16; kk += 4) {
        const int kc4 = (kt << 4) + kk;
        f32x4 u[4], w[4];
#pragma unroll
        for (int bi = 0; bi < 4; ++bi)
          u[bi] = *(const f32x4*)(ubuf + uswz((bt << 2) + bi, kc4));
        const int kx = (kc << 7) + kc4;
#pragma unroll
        for (int ri = 0; ri < 4; ++ri)
          w[ri] = *(const f32x4*)(Wsh + wswz((rt << 2) + ri, kx));
#pragma unroll
        for (int ri = 0; ri < 4; ++ri)
#pragma unroll
          for (int bi = 0; bi < 4; ++bi) {
            acc[ri][bi].x = fmaf(u[bi].x, w[ri].x, acc[ri][bi].x);
            acc[ri][bi].y = fmaf(u[bi].y, w[ri].y, acc[ri][bi].y);
            acc[ri][bi].z = fmaf(u[bi].z, w[ri].z, acc[ri][bi].z);
            acc[ri][bi].w = fmaf(u[bi].w, w[ri].w, acc[ri][bi].w);
          }
      }
    };

    // L1 step-start dependency: own h1[s-1] exchange complete.
    if (layer == 1 && s > 0) {
      if (tid == 0) poll_ge(&cnt[1], s * NBLK);
      __builtin_amdgcn_s_barrier();
      __builtin_amdgcn_sched_barrier(0);
    }

    load_chunk(0);

#pragma unroll 1
    for (int i = 0; i < 8; ++i) {
      __builtin_amdgcn_s_barrier();                 // (A) ubuf free
      __builtin_amdgcn_sched_barrier(0);
      asm volatile("s_waitcnt vmcnt(0)" ::: "memory");  // chunk-i loads landed
      __builtin_amdgcn_sched_barrier(0);
#pragma unroll
      for (int j = 0; j < 4; ++j) {
        const int f   = tid + (j << 8);
        const int b   = f >> 5;
        const int kc4 = (f & 31) << 2;
        *(f32x4*)(ubuf + uswz(b, kc4)) = r4[j];
      }
      if (i < 7) {
        if (i == 3) {  // about to issue the cross-dependent half
          if (layer == 0) {
            if (s > 0 && tid == 0) poll_ge(&cnt[0], s * NBLK);
          } else {
            if (tid == 0) poll_ge(&cnt[0], (s + 1) * NBLK);
          }
          __builtin_amdgcn_s_barrier();             // (P) poll visible to all
          __builtin_amdgcn_sched_barrier(0);
        }
        load_chunk(i + 1);                          // prefetch flies during compute
      }
      asm volatile("s_waitcnt lgkmcnt(0)" ::: "memory");
      __builtin_amdgcn_sched_barrier(0);
      __builtin_amdgcn_s_barrier();                 // (B) ubuf visible
      __builtin_amdgcn_sched_barrier(0);
      compute(i);
    }

    // k-split reduction (lanes xor 1,2,4 sum the 8-way split)
    float rv[4][4];
#pragma unroll
    for (int ri = 0; ri < 4; ++ri)
#pragma unroll
      for (int bi = 0; bi < 4; ++bi) {
        float v = (acc[ri][bi].x + acc[ri][bi].y) + (acc[ri][bi].z + acc[ri][bi].w);
        v += __shfl_xor(v, 1, 64);
        v += __shfl_xor(v, 2, 64);
        v += __shfl_xor(v, 4, 64);
        rv[ri][bi] = v;
      }
    __builtin_amdgcn_s_barrier();                   // (C) compute(7) reads done
    __builtin_amdgcn_sched_barrier(0);
    if (kt == 0) {
#pragma unroll
      for (int ri = 0; ri < 4; ++ri)
#pragma unroll
        for (int bi = 0; bi < 4; ++bi)
          gbuf[(((rt << 2) + ri) << 5) + (bt << 2) + bi] = rv[ri][bi];
    }
    // ring backpressure: slot s&3 held step s-4; L1 must have finished step s-3.
    if (layer == 0 && s >= RING && tid == 0) poll_ge(&cnt[1], (s - RING + 1) * NBLK);
    asm volatile("s_waitcnt lgkmcnt(0)" ::: "memory");
    __builtin_amdgcn_sched_barrier(0);
    __builtin_amdgcn_s_barrier();                   // (D) gbuf visible
    __builtin_amdgcn_sched_barrier(0);

    if (tid < 128) {
      const int jj = tid & 3;
      const int b  = tid >> 2;
      const float gi = gbuf[((0 + jj) << 5) + b] + bias_[0];
      const float gf = gbuf[((4 + jj) << 5) + b] + bias_[1];
      const float gg = gbuf[((8 + jj) << 5) + b] + bias_[2];
      const float go = gbuf[((12 + jj) << 5) + b] + bias_[3];
      const float cn = sigf(gf) * creg + sigf(gi) * tanh_(gg);
      const float hn = sigf(go) * tanh_(cn);
      creg = cn;
      const int j = j0 + jj;
      if (layer == 0) {
        st_coh(ring + (((s & (RING - 1)) * BB + b) << 9) + j, hn);
        if (s == TT - 1) out[(size_t)HFO + (b << 9) + j] = hn;
      } else {
        out[((size_t)((b << 11) + s) << 9) + j] = hn;
        st_coh(ring1 + (((s & (RING - 1)) * BB + b) << 9) + j, hn);
        if (s == TT - 1) out[(size_t)HFO + ((BB + b) << 9) + j] = hn;
      }
    }
    __syncthreads();  // (E) vmcnt(0): h/y stores drained before the flag add
    if (tid == 0)
      __hip_atomic_fetch_add(&cnt[layer], 1, __ATOMIC_RELAXED, __HIP_MEMORY_SCOPE_AGENT);
  }

  if (tid < 128) {
    const int jj = tid & 3;
    const int b  = tid >> 2;
    out[(size_t)CFO + ((layer * BB + b) << 9) + (j0 + jj)] = creg;
  }
}

extern "C" void kernel_launch(void* const* d_in, const int* in_sizes, int n_in,
                              void* d_out, int out_size, void* d_ws, size_t ws_size,
                              hipStream_t stream) {
  (void)in_sizes; (void)n_in; (void)out_size; (void)ws_size;
  const float* x    = (const float*)d_in[0];
  const float* Wih0 = (const float*)d_in[1];
  const float* Whh0 = (const float*)d_in[2];
  const float* bih0 = (const float*)d_in[3];
  const float* bhh0 = (const float*)d_in[4];
  const float* Wih1 = (const float*)d_in[5];
  const float* Whh1 = (const float*)d_in[6];
  const float* bih1 = (const float*)d_in[7];
  const float* bhh1 = (const float*)d_in[8];
  const float* h0   = (const float*)d_in[9];
  const float* c0   = (const float*)d_in[10];

  float* out   = (float*)d_out;
  float* ring  = (float*)d_ws;                            // 256 KB
  float* ring1 = (float*)((char*)d_ws + (256 << 10));     // 256 KB
  int*   cnt   = (int*)((char*)d_ws + (512 << 10));

  hipMemsetAsync(cnt, 0, 64, stream);

  hipLaunchKernelGGL(lstm_persist, dim3(2 * NBLK), dim3(256), 0, stream,
                     x, Wih0, Whh0, bih0, bhh0, Wih1, Whh1, bih1, bhh1,
                     h0, c0, out, ring, ring1, cnt);
}